// Round 1
// baseline (3677.407 us; speedup 1.0000x reference)
//
#include <hip/hip_runtime.h>
#include <hip/hip_bf16.h>

#define N_NODES 50000
#define N_EDGES 800000
#define HID 64
#define E_FEAT 16

// ---------------------------------------------------------------------------
// deg count: atomicAdd 1 at col
__global__ void deg_kernel(const int* __restrict__ col, float* __restrict__ deg, int E) {
    int tid = blockIdx.x * blockDim.x + threadIdx.x;
    int stride = gridDim.x * blockDim.x;
    for (int e = tid; e < E; e += stride) {
        atomicAdd(&deg[col[e]], 1.0f);
    }
}

// dinv = rsqrt(deg + 1)   (+1 = self loop)
__global__ void dinv_kernel(float* __restrict__ deg, int N) {
    int i = blockIdx.x * blockDim.x + threadIdx.x;
    if (i < N) deg[i] = rsqrtf(deg[i] + 1.0f);
}

// ---------------------------------------------------------------------------
// Y[row][f] = sum_k X[row][k] * W[k][f]   (X: N x 64, W: 64 x 64)
// one wave per row; lane f owns output feature f; broadcast X via shfl.
__global__ void gemm64_kernel(const float* __restrict__ X, const float* __restrict__ W,
                              float* __restrict__ Y, int N) {
    int lane = threadIdx.x & 63;
    int row = blockIdx.x * (blockDim.x >> 6) + (threadIdx.x >> 6);
    if (row >= N) return;
    float xv = X[row * 64 + lane];
    float acc = 0.0f;
#pragma unroll
    for (int k = 0; k < 64; ++k) {
        acc += __shfl(xv, k) * W[k * 64 + lane];
    }
    Y[row * 64 + lane] = acc;
}

// ---------------------------------------------------------------------------
// scatter aggregate: out[col][f] += h[row][f] * dinv[row]*dinv[col]
// one wave per edge (lane = feature)
__global__ void aggregate_kernel(const float* __restrict__ h,
                                 const int* __restrict__ row, const int* __restrict__ col,
                                 const float* __restrict__ dinv,
                                 float* __restrict__ out, int E) {
    int lane = threadIdx.x & 63;
    int wave = blockIdx.x * (blockDim.x >> 6) + (threadIdx.x >> 6);
    int nwaves = gridDim.x * (blockDim.x >> 6);
    for (int e = wave; e < E; e += nwaves) {
        int r = row[e];
        int c = col[e];
        float nrm = dinv[r] * dinv[c];
        atomicAdd(&out[c * 64 + lane], h[r * 64 + lane] * nrm);
    }
}

// agg[i][f] = (relu?) (agg[i][f] + h[i][f]*dinv[i]^2 + b[f])
template <bool RELU>
__global__ void finalize_kernel(float* __restrict__ agg, const float* __restrict__ h,
                                const float* __restrict__ dinv, const float* __restrict__ b,
                                int N) {
    int i = blockIdx.x * blockDim.x + threadIdx.x;
    if (i >= N * 64) return;
    int node = i >> 6;
    int f = i & 63;
    float d = dinv[node];
    float v = agg[i] + h[i] * d * d + b[f];
    agg[i] = RELU ? fmaxf(v, 0.0f) : v;
}

// ---------------------------------------------------------------------------
// edge MLP: out[e] = relu(concat(h[row],h[col],eAtt) @ mW1 + mb1) @ mW2 + mb2
// one wave per edge; mW1 staged in LDS; lane j computes hidden unit j.
__global__ void edge_mlp_kernel(const float* __restrict__ h,
                                const int* __restrict__ row, const int* __restrict__ col,
                                const float* __restrict__ eAtt,
                                const float* __restrict__ mW1, const float* __restrict__ mb1,
                                const float* __restrict__ mW2, const float* __restrict__ mb2,
                                float* __restrict__ out, int E) {
    __shared__ float Wlds[144 * 64];
    __shared__ float w2lds[64];
    for (int i = threadIdx.x; i < 144 * 64; i += blockDim.x) Wlds[i] = mW1[i];
    if (threadIdx.x < 64) w2lds[threadIdx.x] = mW2[threadIdx.x];
    __syncthreads();

    int lane = threadIdx.x & 63;
    int wave = blockIdx.x * (blockDim.x >> 6) + (threadIdx.x >> 6);
    int nwaves = gridDim.x * (blockDim.x >> 6);
    float bias = mb1[lane];
    float w2 = w2lds[lane];
    float b2v = mb2[0];

    for (int e = wave; e < E; e += nwaves) {
        int r = row[e];
        int c = col[e];
        float hr = h[r * 64 + lane];
        float hc = h[c * 64 + lane];
        float ea = (lane < E_FEAT) ? eAtt[e * E_FEAT + lane] : 0.0f;
        float acc = bias;
#pragma unroll
        for (int k = 0; k < 64; ++k) acc += __shfl(hr, k) * Wlds[k * 64 + lane];
#pragma unroll
        for (int k = 0; k < 64; ++k) acc += __shfl(hc, k) * Wlds[(64 + k) * 64 + lane];
#pragma unroll
        for (int k = 0; k < E_FEAT; ++k) acc += __shfl(ea, k) * Wlds[(128 + k) * 64 + lane];
        float t = fmaxf(acc, 0.0f) * w2;
#pragma unroll
        for (int off = 32; off > 0; off >>= 1) t += __shfl_xor(t, off);
        if (lane == 0) out[e] = t + b2v;
    }
}

// ---------------------------------------------------------------------------
extern "C" void kernel_launch(void* const* d_in, const int* in_sizes, int n_in,
                              void* d_out, int out_size, void* d_ws, size_t ws_size,
                              hipStream_t stream) {
    const float* x    = (const float*)d_in[0];   // [N, 64]
    const int*   eIdx = (const int*)d_in[1];     // [2, E]
    const float* eAtt = (const float*)d_in[2];   // [E, 16]
    const float* W1   = (const float*)d_in[3];   // [64, 64]
    const float* b1   = (const float*)d_in[4];   // [64]
    const float* W2   = (const float*)d_in[5];   // [64, 64]
    const float* b2   = (const float*)d_in[6];   // [64]
    const float* mW1  = (const float*)d_in[7];   // [144, 64]
    const float* mb1  = (const float*)d_in[8];   // [64]
    const float* mW2  = (const float*)d_in[9];   // [64, 1]
    const float* mb2  = (const float*)d_in[10];  // [1]
    float* out = (float*)d_out;                  // [E]

    const int N = N_NODES;
    const int E = N_EDGES;
    const int* row = eIdx;
    const int* col = eIdx + E;

    // workspace layout (floats)
    float* dinv = (float*)d_ws;                  // N
    float* bufA = dinv + ((N + 63) & ~63);       // N*64  (h1 / h2)
    float* bufB = bufA + N * 64;                 // N*64  (h_relu / h_final)

    // --- degrees ---
    hipMemsetAsync(dinv, 0, N * sizeof(float), stream);
    deg_kernel<<<2048, 256, 0, stream>>>(col, dinv, E);
    dinv_kernel<<<(N + 255) / 256, 256, 0, stream>>>(dinv, N);

    // --- layer 1: h1 = x @ W1 ; agg ; relu ---
    gemm64_kernel<<<(N + 3) / 4, 256, 0, stream>>>(x, W1, bufA, N);
    hipMemsetAsync(bufB, 0, (size_t)N * 64 * sizeof(float), stream);
    aggregate_kernel<<<2048, 256, 0, stream>>>(bufA, row, col, dinv, bufB, E);
    finalize_kernel<true><<<(N * 64 + 255) / 256, 256, 0, stream>>>(bufB, bufA, dinv, b1, N);

    // --- layer 2: h2 = h_relu @ W2 ; agg ; (no relu) ---
    gemm64_kernel<<<(N + 3) / 4, 256, 0, stream>>>(bufB, W2, bufA, N);
    hipMemsetAsync(bufB, 0, (size_t)N * 64 * sizeof(float), stream);
    aggregate_kernel<<<2048, 256, 0, stream>>>(bufA, row, col, dinv, bufB, E);
    finalize_kernel<false><<<(N * 64 + 255) / 256, 256, 0, stream>>>(bufB, bufA, dinv, b2, N);

    // --- edge MLP ---
    edge_mlp_kernel<<<2048, 256, 0, stream>>>(bufB, row, col, eAtt, mW1, mb1, mW2, mb2, out, E);
}

// Round 2
// 725.310 us; speedup vs baseline: 5.0701x; 5.0701x over previous
//
#include <hip/hip_runtime.h>
#include <hip/hip_bf16.h>

#define N_NODES 50000
#define N_EDGES 800000
#define E_FEAT 16

// ---------------------------------------------------------------------------
__global__ void deg_kernel(const int* __restrict__ col, float* __restrict__ deg, int E) {
    int e = blockIdx.x * blockDim.x + threadIdx.x;
    if (e < E) atomicAdd(&deg[col[e]], 1.0f);
}

__global__ void dinv_kernel(float* __restrict__ deg, int N) {
    int i = blockIdx.x * blockDim.x + threadIdx.x;
    if (i < N) deg[i] = rsqrtf(deg[i] + 1.0f);
}

// ---------------------------------------------------------------------------
// Y[i][f] = (X[i][:] @ W[:,f]) * (SCALE ? scale[i] : 1) + (BIAS ? bias[f] : 0)
// one wave per row, lane = output feature, W staged in LDS.
// NOTE: no __restrict__ on X/Y — the Q pass runs in-place (each wave reads
// its whole row into a register before writing the same row).
template <bool SCALE, bool BIAS>
__global__ void gemm64_kernel(const float* X, const float* __restrict__ W,
                              const float* __restrict__ scale, const float* __restrict__ bias,
                              float* Y, int N) {
    __shared__ float Wlds[64 * 64];
    for (int i = threadIdx.x; i < 64 * 64; i += blockDim.x) Wlds[i] = W[i];
    __syncthreads();
    int lane = threadIdx.x & 63;
    int r = blockIdx.x * (blockDim.x >> 6) + (threadIdx.x >> 6);
    if (r >= N) return;
    float xv = X[r * 64 + lane];
    float acc = 0.0f;
#pragma unroll
    for (int k = 0; k < 64; ++k) acc += __shfl(xv, k) * Wlds[k * 64 + lane];
    if (SCALE) acc *= scale[r];
    if (BIAS) acc += bias[lane];
    Y[r * 64 + lane] = acc;
}

// ---------------------------------------------------------------------------
// out[col[e]][f] += hs[row[e]][f]      (hs already scaled by dinv[row])
__global__ void aggregate_kernel(const float* __restrict__ hs,
                                 const int* __restrict__ row, const int* __restrict__ col,
                                 float* __restrict__ out, int E) {
    int lane = threadIdx.x & 63;
    int wave = blockIdx.x * (blockDim.x >> 6) + (threadIdx.x >> 6);
    int nwaves = gridDim.x * (blockDim.x >> 6);
    for (int e = wave; e < E; e += nwaves) {
        atomicAdd(&out[col[e] * 64 + lane], hs[row[e] * 64 + lane]);
    }
}

// h_out[i][f] = (relu?) ( dinv[i]*(agg[i][f] + hs[i][f]) + b[f] )
template <bool RELU>
__global__ void finalize_kernel(float* __restrict__ agg, const float* __restrict__ hs,
                                const float* __restrict__ dinv, const float* __restrict__ b,
                                int N) {
    int i = blockIdx.x * blockDim.x + threadIdx.x;
    if (i >= N * 64) return;
    int node = i >> 6;
    int f = i & 63;
    float v = dinv[node] * (agg[i] + hs[i]) + b[f];
    agg[i] = RELU ? fmaxf(v, 0.0f) : v;
}

// ---------------------------------------------------------------------------
// out[e] = sum_j relu(P[row[e]][j] + Q[col[e]][j] + (eAtt[e]@C)[j]) * w2[j] + b2
// 16 lanes per edge; lane sub owns hidden units [4*sub, 4*sub+4) as float4.
// 16 edges per 256-thread block -> coalesced eAtt reads and out writes.
__global__ void edge_mlp2_kernel(const float4* __restrict__ P4, const float4* __restrict__ Q4,
                                 const int* __restrict__ row, const int* __restrict__ col,
                                 const float* __restrict__ eAtt,
                                 const float* __restrict__ mW1,
                                 const float* __restrict__ mW2, const float* __restrict__ mb2,
                                 float* __restrict__ out, int E) {
    __shared__ float4 C4[16 * 16];   // C4[k*16+sub] = mW1 row (128+k), cols [4*sub,4*sub+4)
    __shared__ float4 W24[16];
    __shared__ float b2s;
    {
        int t = threadIdx.x;
        int k = t >> 4, s = t & 15;
        C4[t] = ((const float4*)(mW1 + (128 + k) * 64))[s];
        if (t < 16) W24[t] = ((const float4*)mW2)[t];
        if (t == 0) b2s = mb2[0];
    }
    __syncthreads();

    int sub = threadIdx.x & 15;
    int e = blockIdx.x * 16 + (threadIdx.x >> 4);
    if (e >= E) return;
    int r = row[e];
    int c = col[e];
    float4 p = P4[r * 16 + sub];
    float4 q = Q4[c * 16 + sub];
    float ea = eAtt[e * E_FEAT + sub];

    float4 acc;
    acc.x = p.x + q.x; acc.y = p.y + q.y; acc.z = p.z + q.z; acc.w = p.w + q.w;
#pragma unroll
    for (int k = 0; k < 16; ++k) {
        float a = __shfl(ea, k, 16);
        float4 cv = C4[k * 16 + sub];
        acc.x += a * cv.x; acc.y += a * cv.y; acc.z += a * cv.z; acc.w += a * cv.w;
    }
    float4 w = W24[sub];
    float t = fmaxf(acc.x, 0.0f) * w.x + fmaxf(acc.y, 0.0f) * w.y
            + fmaxf(acc.z, 0.0f) * w.z + fmaxf(acc.w, 0.0f) * w.w;
    t += __shfl_xor(t, 1, 16);
    t += __shfl_xor(t, 2, 16);
    t += __shfl_xor(t, 4, 16);
    t += __shfl_xor(t, 8, 16);
    if (sub == 0) out[e] = t + b2s;
}

// ---------------------------------------------------------------------------
extern "C" void kernel_launch(void* const* d_in, const int* in_sizes, int n_in,
                              void* d_out, int out_size, void* d_ws, size_t ws_size,
                              hipStream_t stream) {
    const float* x    = (const float*)d_in[0];   // [N, 64]
    const int*   eIdx = (const int*)d_in[1];     // [2, E]
    const float* eAtt = (const float*)d_in[2];   // [E, 16]
    const float* W1   = (const float*)d_in[3];   // [64, 64]
    const float* b1   = (const float*)d_in[4];   // [64]
    const float* W2   = (const float*)d_in[5];   // [64, 64]
    const float* b2   = (const float*)d_in[6];   // [64]
    const float* mW1  = (const float*)d_in[7];   // [144, 64] rows: A(0:64), B(64:128), C(128:144)
    const float* mb1  = (const float*)d_in[8];   // [64]
    const float* mW2  = (const float*)d_in[9];   // [64, 1]
    const float* mb2  = (const float*)d_in[10];  // [1]
    float* out = (float*)d_out;                  // [E]

    const int N = N_NODES;
    const int E = N_EDGES;
    const int* row = eIdx;
    const int* col = eIdx + E;

    // workspace: dinv | bufA (N*64) | bufB (N*64)
    float* dinv = (float*)d_ws;
    float* bufA = dinv + ((N + 63) & ~63);
    float* bufB = bufA + N * 64;

    const int gemmBlocks = (N + 3) / 4;

    // --- degrees ---
    hipMemsetAsync(dinv, 0, N * sizeof(float), stream);
    deg_kernel<<<(E + 255) / 256, 256, 0, stream>>>(col, dinv, E);
    dinv_kernel<<<(N + 255) / 256, 256, 0, stream>>>(dinv, N);

    // --- layer 1: hs1 = (x@W1)*dinv ; agg ; h1 = relu(dinv*(agg+hs1)+b1) ---
    gemm64_kernel<true, false><<<gemmBlocks, 256, 0, stream>>>(x, W1, dinv, nullptr, bufA, N);
    hipMemsetAsync(bufB, 0, (size_t)N * 64 * sizeof(float), stream);
    aggregate_kernel<<<4096, 256, 0, stream>>>(bufA, row, col, bufB, E);
    finalize_kernel<true><<<(N * 64 + 255) / 256, 256, 0, stream>>>(bufB, bufA, dinv, b1, N);

    // --- layer 2: hs2 = (h1@W2)*dinv ; agg ; h2 = dinv*(agg+hs2)+b2 ---
    gemm64_kernel<true, false><<<gemmBlocks, 256, 0, stream>>>(bufB, W2, dinv, nullptr, bufA, N);
    hipMemsetAsync(bufB, 0, (size_t)N * 64 * sizeof(float), stream);
    aggregate_kernel<<<4096, 256, 0, stream>>>(bufA, row, col, bufB, E);
    finalize_kernel<false><<<(N * 64 + 255) / 256, 256, 0, stream>>>(bufB, bufA, dinv, b2, N);

    // --- edge MLP decomposition: P = h2@A + mb1 (bufA); Q = h2@B (bufB, in-place) ---
    gemm64_kernel<false, true><<<gemmBlocks, 256, 0, stream>>>(bufB, mW1, nullptr, mb1, bufA, N);
    gemm64_kernel<false, false><<<gemmBlocks, 256, 0, stream>>>(bufB, mW1 + 64 * 64, nullptr, nullptr, bufB, N);

    edge_mlp2_kernel<<<(E + 15) / 16, 256, 0, stream>>>(
        (const float4*)bufA, (const float4*)bufB, row, col, eAtt,
        mW1, mW2, mb2, out, E);
}

// Round 3
// 428.096 us; speedup vs baseline: 8.5901x; 1.6943x over previous
//
#include <hip/hip_runtime.h>
#include <hip/hip_bf16.h>

#define N_NODES 50000
#define N_EDGES 800000
#define E_FEAT 16

// ---------------------------------------------------------------------------
// in-degree histogram (int atomics)
__global__ void deg_kernel(const int* __restrict__ col, int* __restrict__ deg, int E) {
    int e = blockIdx.x * blockDim.x + threadIdx.x;
    if (e < E) atomicAdd(&deg[col[e]], 1);
}

// --- 3-kernel exclusive scan of deg -> off ---------------------------------
__global__ void scanA_kernel(const int* __restrict__ deg, int* __restrict__ off,
                             int* __restrict__ blockSums, int N) {
    __shared__ int s[256];
    int i = blockIdx.x * 256 + threadIdx.x;
    s[threadIdx.x] = (i < N) ? deg[i] : 0;
    __syncthreads();
#pragma unroll
    for (int d = 1; d < 256; d <<= 1) {
        int t = (threadIdx.x >= d) ? s[threadIdx.x - d] : 0;
        __syncthreads();
        s[threadIdx.x] += t;
        __syncthreads();
    }
    if (i < N) off[i] = s[threadIdx.x];                 // inclusive within block
    if (threadIdx.x == 255) blockSums[blockIdx.x] = s[255];
}

__global__ void scanB_kernel(int* __restrict__ blockSums, int nb) {
    __shared__ int s[256];
    int t = threadIdx.x;
    int orig = (t < nb) ? blockSums[t] : 0;
    s[t] = orig;
    __syncthreads();
#pragma unroll
    for (int d = 1; d < 256; d <<= 1) {
        int v = (t >= d) ? s[t - d] : 0;
        __syncthreads();
        s[t] += v;
        __syncthreads();
    }
    if (t < nb) blockSums[t] = s[t] - orig;             // exclusive
}

// off -> global exclusive scan; also dinv = rsqrt(deg+1)
__global__ void scanC_kernel(const int* __restrict__ deg, int* __restrict__ off,
                             const int* __restrict__ blockSums, float* __restrict__ dinv,
                             int N) {
    int i = blockIdx.x * 256 + threadIdx.x;
    if (i >= N) return;
    off[i] += blockSums[blockIdx.x] - deg[i];
    dinv[i] = rsqrtf((float)deg[i] + 1.0f);
}

// srcIdx[off[c] + rank] = row  (rank via int atomic)
__global__ void scatter_kernel(const int* __restrict__ row, const int* __restrict__ col,
                               const int* __restrict__ off, int* __restrict__ cnt,
                               int* __restrict__ srcIdx, int E) {
    int e = blockIdx.x * blockDim.x + threadIdx.x;
    if (e >= E) return;
    int c = col[e];
    int pos = atomicAdd(&cnt[c], 1);
    srcIdx[off[c] + pos] = row[e];
}

// ---------------------------------------------------------------------------
// Y[i][f] = (X[i][:] @ W[:,f]) * (SCALE ? scale[i] : 1); W staged in LDS.
template <bool SCALE>
__global__ void gemm64_kernel(const float* __restrict__ X, const float* __restrict__ W,
                              const float* __restrict__ scale, float* __restrict__ Y, int N) {
    __shared__ float Wlds[64 * 64];
    for (int i = threadIdx.x; i < 64 * 64; i += blockDim.x) Wlds[i] = W[i];
    __syncthreads();
    int lane = threadIdx.x & 63;
    int r = blockIdx.x * (blockDim.x >> 6) + (threadIdx.x >> 6);
    if (r >= N) return;
    float xv = X[r * 64 + lane];
    float acc = 0.0f;
#pragma unroll
    for (int k = 0; k < 64; ++k) acc += __shfl(xv, k) * Wlds[k * 64 + lane];
    if (SCALE) acc *= scale[r];
    Y[r * 64 + lane] = acc;
}

// dual GEMM: P = X@WA + biasP, Q = X@WB (Q may alias X: row read before write)
__global__ void gemmPQ_kernel(const float* X, const float* __restrict__ WA,
                              const float* __restrict__ WB, const float* __restrict__ biasP,
                              float* P, float* Q, int N) {
    __shared__ float WAl[64 * 64];
    __shared__ float WBl[64 * 64];
    for (int i = threadIdx.x; i < 64 * 64; i += blockDim.x) { WAl[i] = WA[i]; WBl[i] = WB[i]; }
    __syncthreads();
    int lane = threadIdx.x & 63;
    int r = blockIdx.x * (blockDim.x >> 6) + (threadIdx.x >> 6);
    if (r >= N) return;
    float xv = X[r * 64 + lane];
    float accP = biasP[lane];
    float accQ = 0.0f;
#pragma unroll
    for (int k = 0; k < 64; ++k) {
        float xk = __shfl(xv, k);
        accP += xk * WAl[k * 64 + lane];
        accQ += xk * WBl[k * 64 + lane];
    }
    P[r * 64 + lane] = accP;
    Q[r * 64 + lane] = accQ;
}

// ---------------------------------------------------------------------------
// CSR segment-sum + finalize: out[n] = (relu?)(dinv[n]*(hs[n] + sum_in hs[src]) + b)
template <bool RELU>
__global__ void agg_csr_kernel(const float* __restrict__ hs,
                               const int* __restrict__ off, const int* __restrict__ deg,
                               const int* __restrict__ srcIdx,
                               const float* __restrict__ dinv, const float* __restrict__ b,
                               float* __restrict__ out, int N) {
    int lane = threadIdx.x & 63;
    int n = blockIdx.x * (blockDim.x >> 6) + (threadIdx.x >> 6);
    if (n >= N) return;
    int o = off[n];
    int d = deg[n];
    float acc = hs[n * 64 + lane];                       // self loop
    int j = 0;
    for (; j + 4 <= d; j += 4) {                         // 4 gathers in flight
        int s0 = srcIdx[o + j], s1 = srcIdx[o + j + 1];
        int s2 = srcIdx[o + j + 2], s3 = srcIdx[o + j + 3];
        float a0 = hs[s0 * 64 + lane], a1 = hs[s1 * 64 + lane];
        float a2 = hs[s2 * 64 + lane], a3 = hs[s3 * 64 + lane];
        acc += (a0 + a1) + (a2 + a3);
    }
    for (; j < d; ++j) acc += hs[srcIdx[o + j] * 64 + lane];
    float v = dinv[n] * acc + b[lane];
    out[n * 64 + lane] = RELU ? fmaxf(v, 0.0f) : v;
}

// ---------------------------------------------------------------------------
// out[e] = sum_j relu(P[row[e]][j] + Q[col[e]][j] + (eAtt[e]@C)[j]) * w2[j] + b2
// 16 lanes per edge; lane sub owns 4 hidden units as float4.
__global__ void edge_mlp2_kernel(const float4* __restrict__ P4, const float4* __restrict__ Q4,
                                 const int* __restrict__ row, const int* __restrict__ col,
                                 const float* __restrict__ eAtt,
                                 const float* __restrict__ mW1,
                                 const float* __restrict__ mW2, const float* __restrict__ mb2,
                                 float* __restrict__ out, int E) {
    __shared__ float4 C4[16 * 16];
    __shared__ float4 W24[16];
    __shared__ float b2s;
    {
        int t = threadIdx.x;
        int k = t >> 4, s = t & 15;
        C4[t] = ((const float4*)(mW1 + (128 + k) * 64))[s];
        if (t < 16) W24[t] = ((const float4*)mW2)[t];
        if (t == 0) b2s = mb2[0];
    }
    __syncthreads();

    int sub = threadIdx.x & 15;
    int e = blockIdx.x * 16 + (threadIdx.x >> 4);
    if (e >= E) return;
    int r = row[e];
    int c = col[e];
    float4 p = P4[r * 16 + sub];
    float4 q = Q4[c * 16 + sub];
    float ea = eAtt[e * E_FEAT + sub];

    float4 acc;
    acc.x = p.x + q.x; acc.y = p.y + q.y; acc.z = p.z + q.z; acc.w = p.w + q.w;
#pragma unroll
    for (int k = 0; k < 16; ++k) {
        float a = __shfl(ea, k, 16);
        float4 cv = C4[k * 16 + sub];
        acc.x += a * cv.x; acc.y += a * cv.y; acc.z += a * cv.z; acc.w += a * cv.w;
    }
    float4 w = W24[sub];
    float t = fmaxf(acc.x, 0.0f) * w.x + fmaxf(acc.y, 0.0f) * w.y
            + fmaxf(acc.z, 0.0f) * w.z + fmaxf(acc.w, 0.0f) * w.w;
    t += __shfl_xor(t, 1, 16);
    t += __shfl_xor(t, 2, 16);
    t += __shfl_xor(t, 4, 16);
    t += __shfl_xor(t, 8, 16);
    if (sub == 0) out[e] = t + b2s;
}

// ---------------------------------------------------------------------------
extern "C" void kernel_launch(void* const* d_in, const int* in_sizes, int n_in,
                              void* d_out, int out_size, void* d_ws, size_t ws_size,
                              hipStream_t stream) {
    const float* x    = (const float*)d_in[0];   // [N, 64]
    const int*   eIdx = (const int*)d_in[1];     // [2, E]
    const float* eAtt = (const float*)d_in[2];   // [E, 16]
    const float* W1   = (const float*)d_in[3];
    const float* b1   = (const float*)d_in[4];
    const float* W2   = (const float*)d_in[5];
    const float* b2   = (const float*)d_in[6];
    const float* mW1  = (const float*)d_in[7];   // [144,64]: A(0:64), B(64:128), C(128:144)
    const float* mb1  = (const float*)d_in[8];
    const float* mW2  = (const float*)d_in[9];
    const float* mb2  = (const float*)d_in[10];
    float* out = (float*)d_out;                  // [E]

    const int N = N_NODES;
    const int E = N_EDGES;
    const int* row = eIdx;
    const int* col = eIdx + E;

    // workspace layout (everything 16B-aligned by construction)
    int*   deg_i  = (int*)d_ws;                  // N
    int*   cnt    = deg_i + N;                   // N   (memset deg+cnt together)
    int*   off    = cnt + N;                     // N
    int*   bsum   = off + N;                     // 256
    float* dinv   = (float*)(bsum + 256);        // N
    int*   srcIdx = (int*)(dinv + N);            // E
    float* bufA   = (float*)(srcIdx + ((E + 63) & ~63)); // N*64
    float* bufB   = bufA + (size_t)N * 64;               // N*64

    const int gemmBlocks = (N + 3) / 4;
    const int scanBlocks = (N + 255) / 256;      // 196

    // --- CSR build ---
    hipMemsetAsync(deg_i, 0, 2 * N * sizeof(int), stream);   // deg + cnt
    deg_kernel<<<(E + 255) / 256, 256, 0, stream>>>(col, deg_i, E);
    scanA_kernel<<<scanBlocks, 256, 0, stream>>>(deg_i, off, bsum, N);
    scanB_kernel<<<1, 256, 0, stream>>>(bsum, scanBlocks);
    scanC_kernel<<<scanBlocks, 256, 0, stream>>>(deg_i, off, bsum, dinv, N);
    scatter_kernel<<<(E + 255) / 256, 256, 0, stream>>>(row, col, off, cnt, srcIdx, E);

    // --- layer 1 ---
    gemm64_kernel<true><<<gemmBlocks, 256, 0, stream>>>(x, W1, dinv, bufA, N);
    agg_csr_kernel<true><<<gemmBlocks, 256, 0, stream>>>(bufA, off, deg_i, srcIdx, dinv, b1, bufB, N);

    // --- layer 2 ---
    gemm64_kernel<true><<<gemmBlocks, 256, 0, stream>>>(bufB, W2, dinv, bufA, N);
    agg_csr_kernel<false><<<gemmBlocks, 256, 0, stream>>>(bufA, off, deg_i, srcIdx, dinv, b2, bufB, N);

    // --- edge MLP decomposition: P = h2@A + mb1 -> bufA ; Q = h2@B -> bufB (in-place) ---
    gemmPQ_kernel<<<gemmBlocks, 256, 0, stream>>>(bufB, mW1, mW1 + 64 * 64, mb1, bufA, bufB, N);

    edge_mlp2_kernel<<<(E + 15) / 16, 256, 0, stream>>>(
        (const float4*)bufA, (const float4*)bufB, row, col, eAtt,
        mW1, mW2, mb2, out, E);
}

// Round 4
// 420.221 us; speedup vs baseline: 8.7511x; 1.0187x over previous
//
#include <hip/hip_runtime.h>
#include <hip/hip_bf16.h>
#include <hip/hip_fp16.h>

#define N_NODES 50000
#define N_EDGES 800000
#define E_FEAT 16

// ---------------------------------------------------------------------------
// in-degree histogram (int atomics)
__global__ void deg_kernel(const int* __restrict__ col, int* __restrict__ deg, int E) {
    int e = blockIdx.x * blockDim.x + threadIdx.x;
    if (e < E) atomicAdd(&deg[col[e]], 1);
}

// --- 3-kernel exclusive scan of deg -> off ---------------------------------
__global__ void scanA_kernel(const int* __restrict__ deg, int* __restrict__ off,
                             int* __restrict__ blockSums, int N) {
    __shared__ int s[256];
    int i = blockIdx.x * 256 + threadIdx.x;
    s[threadIdx.x] = (i < N) ? deg[i] : 0;
    __syncthreads();
#pragma unroll
    for (int d = 1; d < 256; d <<= 1) {
        int t = (threadIdx.x >= d) ? s[threadIdx.x - d] : 0;
        __syncthreads();
        s[threadIdx.x] += t;
        __syncthreads();
    }
    if (i < N) off[i] = s[threadIdx.x];                 // inclusive within block
    if (threadIdx.x == 255) blockSums[blockIdx.x] = s[255];
}

__global__ void scanB_kernel(int* __restrict__ blockSums, int nb) {
    __shared__ int s[256];
    int t = threadIdx.x;
    int orig = (t < nb) ? blockSums[t] : 0;
    s[t] = orig;
    __syncthreads();
#pragma unroll
    for (int d = 1; d < 256; d <<= 1) {
        int v = (t >= d) ? s[t - d] : 0;
        __syncthreads();
        s[t] += v;
        __syncthreads();
    }
    if (t < nb) blockSums[t] = s[t] - orig;             // exclusive
}

// off -> global exclusive scan; dinv = rsqrt(deg+1); cnt = scatter cursor init
__global__ void scanC_kernel(const int* __restrict__ deg, int* __restrict__ off,
                             const int* __restrict__ blockSums, float* __restrict__ dinv,
                             int* __restrict__ cnt, int N) {
    int i = blockIdx.x * 256 + threadIdx.x;
    if (i >= N) return;
    int o = off[i] + blockSums[blockIdx.x] - deg[i];
    off[i] = o;
    cnt[i] = o;
    dinv[i] = rsqrtf((float)deg[i] + 1.0f);
}

// srcIdx[cnt[c]++] = row
__global__ void scatter_kernel(const int* __restrict__ row, const int* __restrict__ col,
                               int* __restrict__ cnt, int* __restrict__ srcIdx, int E) {
    int e = blockIdx.x * blockDim.x + threadIdx.x;
    if (e >= E) return;
    int pos = atomicAdd(&cnt[col[e]], 1);
    srcIdx[pos] = row[e];
}

// ---------------------------------------------------------------------------
// Y16[i][f] = half( (X[i][:] @ W[:,f]) * scale[i] ); W staged in LDS.
__global__ void gemm64h_kernel(const float* __restrict__ X, const float* __restrict__ W,
                               const float* __restrict__ scale, __half* __restrict__ Y16,
                               int N) {
    __shared__ float Wlds[64 * 64];
    for (int i = threadIdx.x; i < 64 * 64; i += blockDim.x) Wlds[i] = W[i];
    __syncthreads();
    int lane = threadIdx.x & 63;
    int r = blockIdx.x * (blockDim.x >> 6) + (threadIdx.x >> 6);
    if (r >= N) return;
    float xv = X[r * 64 + lane];
    float acc = 0.0f;
#pragma unroll
    for (int k = 0; k < 64; ++k) acc += __shfl(xv, k) * Wlds[k * 64 + lane];
    Y16[r * 64 + lane] = __float2half_rn(acc * scale[r]);
}

// dual GEMM: P16 = half(X@WA + biasP), Q16 = half(X@WB)
__global__ void gemmPQh_kernel(const float* __restrict__ X, const float* __restrict__ WA,
                               const float* __restrict__ WB, const float* __restrict__ biasP,
                               __half* __restrict__ P16, __half* __restrict__ Q16, int N) {
    __shared__ float WAl[64 * 64];
    __shared__ float WBl[64 * 64];
    for (int i = threadIdx.x; i < 64 * 64; i += blockDim.x) { WAl[i] = WA[i]; WBl[i] = WB[i]; }
    __syncthreads();
    int lane = threadIdx.x & 63;
    int r = blockIdx.x * (blockDim.x >> 6) + (threadIdx.x >> 6);
    if (r >= N) return;
    float xv = X[r * 64 + lane];
    float accP = biasP[lane];
    float accQ = 0.0f;
#pragma unroll
    for (int k = 0; k < 64; ++k) {
        float xk = __shfl(xv, k);
        accP += xk * WAl[k * 64 + lane];
        accQ += xk * WBl[k * 64 + lane];
    }
    P16[r * 64 + lane] = __float2half_rn(accP);
    Q16[r * 64 + lane] = __float2half_rn(accQ);
}

// ---------------------------------------------------------------------------
// CSR segment-sum + finalize, fp16 gathers.
// Lane l: half-wave hl = l>>5 handles edges j ≡ hl (mod 2); sub = l&31 owns
// features (2sub, 2sub+1) as one __half2 dword. Halves combined via shfl^32.
template <bool RELU>
__global__ void agg_csr_kernel(const __half2* __restrict__ hs2,
                               const int* __restrict__ off, const int* __restrict__ deg,
                               const int* __restrict__ srcIdx,
                               const float* __restrict__ dinv, const float* __restrict__ b,
                               float2* __restrict__ out, int N) {
    int lane = threadIdx.x & 63;
    int n = blockIdx.x * (blockDim.x >> 6) + (threadIdx.x >> 6);
    if (n >= N) return;
    int hl = lane >> 5;
    int sub = lane & 31;
    int o = off[n];
    int d = deg[n];
    float accx = 0.0f, accy = 0.0f;
    if (hl == 0) {                                       // self loop (count once)
        float2 s = __half22float2(hs2[n * 32 + sub]);
        accx = s.x; accy = s.y;
    }
    int j = hl;
    for (; j + 2 < d; j += 4) {                          // 2 gathers in flight / half-wave
        int s0 = srcIdx[o + j];
        int s1 = srcIdx[o + j + 2];
        float2 v0 = __half22float2(hs2[s0 * 32 + sub]);
        float2 v1 = __half22float2(hs2[s1 * 32 + sub]);
        accx += v0.x + v1.x;
        accy += v0.y + v1.y;
    }
    for (; j < d; j += 2) {
        float2 v = __half22float2(hs2[srcIdx[o + j] * 32 + sub]);
        accx += v.x; accy += v.y;
    }
    accx += __shfl(accx, lane ^ 32);
    accy += __shfl(accy, lane ^ 32);
    if (hl == 0) {
        float dv = dinv[n];
        float vx = dv * accx + b[2 * sub];
        float vy = dv * accy + b[2 * sub + 1];
        if (RELU) { vx = fmaxf(vx, 0.0f); vy = fmaxf(vy, 0.0f); }
        out[n * 32 + sub] = make_float2(vx, vy);
    }
}

// ---------------------------------------------------------------------------
// out[e] = sum_j relu(P[row[e]][j] + Q[col[e]][j] + (eAtt[e]@C)[j]) * w2[j] + b2
// 16 lanes per edge; lane sub owns 4 hidden units; P/Q gathered as fp16 (8B/lane).
__global__ void edge_mlp2_kernel(const float2* __restrict__ P2, const float2* __restrict__ Q2,
                                 const int* __restrict__ row, const int* __restrict__ col,
                                 const float* __restrict__ eAtt,
                                 const float* __restrict__ mW1,
                                 const float* __restrict__ mW2, const float* __restrict__ mb2,
                                 float* __restrict__ out, int E) {
    __shared__ float4 C4[16 * 16];
    __shared__ float4 W24[16];
    __shared__ float b2s;
    {
        int t = threadIdx.x;
        int k = t >> 4, s = t & 15;
        C4[t] = ((const float4*)(mW1 + (128 + k) * 64))[s];
        if (t < 16) W24[t] = ((const float4*)mW2)[t];
        if (t == 0) b2s = mb2[0];
    }
    __syncthreads();

    int sub = threadIdx.x & 15;
    int e = blockIdx.x * 16 + (threadIdx.x >> 4);
    if (e >= E) return;
    int r = row[e];
    int c = col[e];
    float2 praw = P2[r * 16 + sub];   // 4 halves = features 4sub..4sub+3
    float2 qraw = Q2[c * 16 + sub];
    float ea = eAtt[e * E_FEAT + sub];

    float2 p01 = __half22float2(*(const __half2*)&praw.x);
    float2 p23 = __half22float2(*(const __half2*)&praw.y);
    float2 q01 = __half22float2(*(const __half2*)&qraw.x);
    float2 q23 = __half22float2(*(const __half2*)&qraw.y);

    float4 acc;
    acc.x = p01.x + q01.x; acc.y = p01.y + q01.y;
    acc.z = p23.x + q23.x; acc.w = p23.y + q23.y;
#pragma unroll
    for (int k = 0; k < 16; ++k) {
        float a = __shfl(ea, k, 16);
        float4 cv = C4[k * 16 + sub];
        acc.x += a * cv.x; acc.y += a * cv.y; acc.z += a * cv.z; acc.w += a * cv.w;
    }
    float4 w = W24[sub];
    float t = fmaxf(acc.x, 0.0f) * w.x + fmaxf(acc.y, 0.0f) * w.y
            + fmaxf(acc.z, 0.0f) * w.z + fmaxf(acc.w, 0.0f) * w.w;
    t += __shfl_xor(t, 1, 16);
    t += __shfl_xor(t, 2, 16);
    t += __shfl_xor(t, 4, 16);
    t += __shfl_xor(t, 8, 16);
    if (sub == 0) out[e] = t + b2s;
}

// ---------------------------------------------------------------------------
extern "C" void kernel_launch(void* const* d_in, const int* in_sizes, int n_in,
                              void* d_out, int out_size, void* d_ws, size_t ws_size,
                              hipStream_t stream) {
    const float* x    = (const float*)d_in[0];   // [N, 64]
    const int*   eIdx = (const int*)d_in[1];     // [2, E]
    const float* eAtt = (const float*)d_in[2];   // [E, 16]
    const float* W1   = (const float*)d_in[3];
    const float* b1   = (const float*)d_in[4];
    const float* W2   = (const float*)d_in[5];
    const float* b2   = (const float*)d_in[6];
    const float* mW1  = (const float*)d_in[7];   // [144,64]: A(0:64), B(64:128), C(128:144)
    const float* mb1  = (const float*)d_in[8];
    const float* mW2  = (const float*)d_in[9];
    const float* mb2  = (const float*)d_in[10];
    float* out = (float*)d_out;                  // [E]

    const int N = N_NODES;
    const int E = N_EDGES;
    const int* row = eIdx;
    const int* col = eIdx + E;

    // workspace layout (all offsets multiples of 16B)
    int*    deg_i  = (int*)d_ws;                        // N
    int*    cnt    = deg_i + N;                         // N
    int*    off    = cnt + N;                           // N
    int*    bsum   = off + N;                           // 256
    float*  dinv   = (float*)(bsum + 256);              // N
    int*    srcIdx = (int*)(dinv + N);                  // E
    __half* h16    = (__half*)(srcIdx + ((E + 63) & ~63)); // N*64*2 halves (hs / P16+Q16)
    float*  bufB   = (float*)(h16 + (size_t)2 * N * 64);   // N*64 f32
    __half* P16    = h16;
    __half* Q16    = h16 + (size_t)N * 64;

    const int gemmBlocks = (N + 3) / 4;
    const int scanBlocks = (N + 255) / 256;

    // --- CSR build ---
    hipMemsetAsync(deg_i, 0, N * sizeof(int), stream);
    deg_kernel<<<(E + 255) / 256, 256, 0, stream>>>(col, deg_i, E);
    scanA_kernel<<<scanBlocks, 256, 0, stream>>>(deg_i, off, bsum, N);
    scanB_kernel<<<1, 256, 0, stream>>>(bsum, scanBlocks);
    scanC_kernel<<<scanBlocks, 256, 0, stream>>>(deg_i, off, bsum, dinv, cnt, N);
    scatter_kernel<<<(E + 255) / 256, 256, 0, stream>>>(row, col, cnt, srcIdx, E);

    // --- layer 1 ---
    gemm64h_kernel<<<gemmBlocks, 256, 0, stream>>>(x, W1, dinv, h16, N);
    agg_csr_kernel<true><<<gemmBlocks, 256, 0, stream>>>(
        (const __half2*)h16, off, deg_i, srcIdx, dinv, b1, (float2*)bufB, N);

    // --- layer 2 ---
    gemm64h_kernel<<<gemmBlocks, 256, 0, stream>>>(bufB, W2, dinv, h16, N);
    agg_csr_kernel<false><<<gemmBlocks, 256, 0, stream>>>(
        (const __half2*)h16, off, deg_i, srcIdx, dinv, b2, (float2*)bufB, N);

    // --- edge MLP decomposition: P16 = h2@A + mb1, Q16 = h2@B ---
    gemmPQh_kernel<<<gemmBlocks, 256, 0, stream>>>(bufB, mW1, mW1 + 64 * 64, mb1, P16, Q16, N);

    edge_mlp2_kernel<<<(E + 15) / 16, 256, 0, stream>>>(
        (const float2*)P16, (const float2*)Q16, row, col, eAtt,
        mW1, mW2, mb2, out, E);
}

// Round 5
// 311.397 us; speedup vs baseline: 11.8094x; 1.3495x over previous
//
#include <hip/hip_runtime.h>
#include <hip/hip_bf16.h>
#include <hip/hip_fp16.h>

#define N_NODES 50000
#define N_EDGES 800000
#define E_FEAT 16

// ---------------------------------------------------------------------------
// in-degree histogram (int atomics)
__global__ void deg_kernel(const int* __restrict__ col, int* __restrict__ deg, int E) {
    int e = blockIdx.x * blockDim.x + threadIdx.x;
    if (e < E) atomicAdd(&deg[col[e]], 1);
}

// --- 3-kernel exclusive scan of deg -> off ---------------------------------
__global__ void scanA_kernel(const int* __restrict__ deg, int* __restrict__ off,
                             int* __restrict__ blockSums, int N) {
    __shared__ int s[256];
    int i = blockIdx.x * 256 + threadIdx.x;
    s[threadIdx.x] = (i < N) ? deg[i] : 0;
    __syncthreads();
#pragma unroll
    for (int d = 1; d < 256; d <<= 1) {
        int t = (threadIdx.x >= d) ? s[threadIdx.x - d] : 0;
        __syncthreads();
        s[threadIdx.x] += t;
        __syncthreads();
    }
    if (i < N) off[i] = s[threadIdx.x];                 // inclusive within block
    if (threadIdx.x == 255) blockSums[blockIdx.x] = s[255];
}

__global__ void scanB_kernel(int* __restrict__ blockSums, int nb) {
    __shared__ int s[256];
    int t = threadIdx.x;
    int orig = (t < nb) ? blockSums[t] : 0;
    s[t] = orig;
    __syncthreads();
#pragma unroll
    for (int d = 1; d < 256; d <<= 1) {
        int v = (t >= d) ? s[t - d] : 0;
        __syncthreads();
        s[t] += v;
        __syncthreads();
    }
    if (t < nb) blockSums[t] = s[t] - orig;             // exclusive
}

// off -> global exclusive scan; dinv = rsqrt(deg+1); cnt = scatter cursor init
__global__ void scanC_kernel(const int* __restrict__ deg, int* __restrict__ off,
                             const int* __restrict__ blockSums, float* __restrict__ dinv,
                             int* __restrict__ cnt, int N) {
    int i = blockIdx.x * 256 + threadIdx.x;
    if (i >= N) return;
    int o = off[i] + blockSums[blockIdx.x] - deg[i];
    off[i] = o;
    cnt[i] = o;
    dinv[i] = rsqrtf((float)deg[i] + 1.0f);
}

// srcIdx[cnt[c]++] = row
__global__ void scatter_kernel(const int* __restrict__ row, const int* __restrict__ col,
                               int* __restrict__ cnt, int* __restrict__ srcIdx, int E) {
    int e = blockIdx.x * blockDim.x + threadIdx.x;
    if (e >= E) return;
    int pos = atomicAdd(&cnt[col[e]], 1);
    srcIdx[pos] = row[e];
}

// ---------------------------------------------------------------------------
// persistent GEMM, W column in VGPRs, X row via wave-uniform scalar loads.
// Y16[r][lane] = half( (X[r][:] @ W[:,lane]) * (SCALE ? scale[r] : 1) )
template <bool SCALE>
__global__ void gemm64_reg_kernel(const float* __restrict__ X, const float* __restrict__ W,
                                  const float* __restrict__ scale, __half* __restrict__ Y16,
                                  int N) {
    int lane = threadIdx.x & 63;
    float w[64];
#pragma unroll
    for (int k = 0; k < 64; ++k) w[k] = W[k * 64 + lane];
    int wid = (blockIdx.x * blockDim.x + threadIdx.x) >> 6;
    int nw = (gridDim.x * blockDim.x) >> 6;
    for (int r0 = wid; r0 < N; r0 += nw) {
        int r = __builtin_amdgcn_readfirstlane(r0);
        const float4* xr = (const float4*)(X + (size_t)r * 64);
        float acc = 0.0f;
#pragma unroll
        for (int k4 = 0; k4 < 16; ++k4) {
            float4 xv = xr[k4];
            acc = fmaf(xv.x, w[4 * k4 + 0], acc);
            acc = fmaf(xv.y, w[4 * k4 + 1], acc);
            acc = fmaf(xv.z, w[4 * k4 + 2], acc);
            acc = fmaf(xv.w, w[4 * k4 + 3], acc);
        }
        if (SCALE) acc *= scale[r];
        Y16[(size_t)r * 64 + lane] = __float2half_rn(acc);
    }
}

// dual persistent GEMM: P16 = half(X@WA + biasP), Q16 = half(X@WB)
__global__ void gemmPQ_reg_kernel(const float* __restrict__ X, const float* __restrict__ WA,
                                  const float* __restrict__ WB, const float* __restrict__ biasP,
                                  __half* __restrict__ P16, __half* __restrict__ Q16, int N) {
    int lane = threadIdx.x & 63;
    float wa[64], wb[64];
#pragma unroll
    for (int k = 0; k < 64; ++k) wa[k] = WA[k * 64 + lane];
#pragma unroll
    for (int k = 0; k < 64; ++k) wb[k] = WB[k * 64 + lane];
    float bp = biasP[lane];
    int wid = (blockIdx.x * blockDim.x + threadIdx.x) >> 6;
    int nw = (gridDim.x * blockDim.x) >> 6;
    for (int r0 = wid; r0 < N; r0 += nw) {
        int r = __builtin_amdgcn_readfirstlane(r0);
        const float4* xr = (const float4*)(X + (size_t)r * 64);
        float accP = bp, accQ = 0.0f;
#pragma unroll
        for (int k4 = 0; k4 < 16; ++k4) {
            float4 xv = xr[k4];
            accP = fmaf(xv.x, wa[4 * k4 + 0], accP); accQ = fmaf(xv.x, wb[4 * k4 + 0], accQ);
            accP = fmaf(xv.y, wa[4 * k4 + 1], accP); accQ = fmaf(xv.y, wb[4 * k4 + 1], accQ);
            accP = fmaf(xv.z, wa[4 * k4 + 2], accP); accQ = fmaf(xv.z, wb[4 * k4 + 2], accQ);
            accP = fmaf(xv.w, wa[4 * k4 + 3], accP); accQ = fmaf(xv.w, wb[4 * k4 + 3], accQ);
        }
        P16[(size_t)r * 64 + lane] = __float2half_rn(accP);
        Q16[(size_t)r * 64 + lane] = __float2half_rn(accQ);
    }
}

// ---------------------------------------------------------------------------
// CSR segment-sum + finalize, fp16 gathers, 4 rows in flight per half-wave.
template <bool RELU>
__global__ void agg_csr_kernel(const __half2* __restrict__ hs2,
                               const int* __restrict__ off, const int* __restrict__ deg,
                               const int* __restrict__ srcIdx,
                               const float* __restrict__ dinv, const float* __restrict__ b,
                               float2* __restrict__ out, int N) {
    int lane = threadIdx.x & 63;
    int n = blockIdx.x * (blockDim.x >> 6) + (threadIdx.x >> 6);
    if (n >= N) return;
    int hl = lane >> 5;
    int sub = lane & 31;
    int o = off[n];
    int d = deg[n];
    float accx = 0.0f, accy = 0.0f;
    if (hl == 0) {                                       // self loop (count once)
        float2 s = __half22float2(hs2[n * 32 + sub]);
        accx = s.x; accy = s.y;
    }
    int j = hl;
    for (; j + 6 < d; j += 8) {                          // 4 gathers in flight / half-wave
        int s0 = srcIdx[o + j],     s1 = srcIdx[o + j + 2];
        int s2 = srcIdx[o + j + 4], s3 = srcIdx[o + j + 6];
        float2 v0 = __half22float2(hs2[s0 * 32 + sub]);
        float2 v1 = __half22float2(hs2[s1 * 32 + sub]);
        float2 v2 = __half22float2(hs2[s2 * 32 + sub]);
        float2 v3 = __half22float2(hs2[s3 * 32 + sub]);
        accx += (v0.x + v1.x) + (v2.x + v3.x);
        accy += (v0.y + v1.y) + (v2.y + v3.y);
    }
    for (; j < d; j += 2) {
        float2 v = __half22float2(hs2[srcIdx[o + j] * 32 + sub]);
        accx += v.x; accy += v.y;
    }
    accx += __shfl(accx, lane ^ 32);
    accy += __shfl(accy, lane ^ 32);
    if (hl == 0) {
        float dv = dinv[n];
        float vx = dv * accx + b[2 * sub];
        float vy = dv * accy + b[2 * sub + 1];
        if (RELU) { vx = fmaxf(vx, 0.0f); vy = fmaxf(vy, 0.0f); }
        out[n * 32 + sub] = make_float2(vx, vy);
    }
}

// ---------------------------------------------------------------------------
// edge MLP, persistent, C+w2 in VGPRs, no LDS / no dynamic shfl in hot loop.
// 16 lanes per edge; lane sub owns hidden units 4sub..4sub+3.
__global__ void edge_mlp3_kernel(const float2* __restrict__ P2, const float2* __restrict__ Q2,
                                 const int* __restrict__ row, const int* __restrict__ col,
                                 const float4* __restrict__ eAtt4,
                                 const float* __restrict__ mW1,
                                 const float* __restrict__ mW2, const float* __restrict__ mb2,
                                 float* __restrict__ out, int E) {
    int sub = threadIdx.x & 15;
    float4 c_reg[16];
#pragma unroll
    for (int k = 0; k < 16; ++k)
        c_reg[k] = ((const float4*)(mW1 + (size_t)(128 + k) * 64))[sub];
    float4 w2 = ((const float4*)mW2)[sub];
    float b2v = mb2[0];

    int slot = blockIdx.x * (blockDim.x >> 4) + (threadIdx.x >> 4);
    int nslots = gridDim.x * (blockDim.x >> 4);

    for (int e = slot; e < E; e += nslots) {
        int r = row[e];
        int c = col[e];
        float2 praw = P2[(size_t)r * 16 + sub];   // 4 halves
        float2 qraw = Q2[(size_t)c * 16 + sub];
        float4 eA = eAtt4[(size_t)e * 4 + 0];
        float4 eB = eAtt4[(size_t)e * 4 + 1];
        float4 eC = eAtt4[(size_t)e * 4 + 2];
        float4 eD = eAtt4[(size_t)e * 4 + 3];

        float2 p01 = __half22float2(*(const __half2*)&praw.x);
        float2 p23 = __half22float2(*(const __half2*)&praw.y);
        float2 q01 = __half22float2(*(const __half2*)&qraw.x);
        float2 q23 = __half22float2(*(const __half2*)&qraw.y);

        float4 acc;
        acc.x = p01.x + q01.x; acc.y = p01.y + q01.y;
        acc.z = p23.x + q23.x; acc.w = p23.y + q23.y;

        float ea[16] = {eA.x, eA.y, eA.z, eA.w, eB.x, eB.y, eB.z, eB.w,
                        eC.x, eC.y, eC.z, eC.w, eD.x, eD.y, eD.z, eD.w};
#pragma unroll
        for (int k = 0; k < 16; ++k) {
            acc.x = fmaf(ea[k], c_reg[k].x, acc.x);
            acc.y = fmaf(ea[k], c_reg[k].y, acc.y);
            acc.z = fmaf(ea[k], c_reg[k].z, acc.z);
            acc.w = fmaf(ea[k], c_reg[k].w, acc.w);
        }
        float t = fmaxf(acc.x, 0.0f) * w2.x + fmaxf(acc.y, 0.0f) * w2.y
                + fmaxf(acc.z, 0.0f) * w2.z + fmaxf(acc.w, 0.0f) * w2.w;
        t += __shfl_xor(t, 1);
        t += __shfl_xor(t, 2);
        t += __shfl_xor(t, 4);
        t += __shfl_xor(t, 8);
        if (sub == 0) out[e] = t + b2v;
    }
}

// ---------------------------------------------------------------------------
extern "C" void kernel_launch(void* const* d_in, const int* in_sizes, int n_in,
                              void* d_out, int out_size, void* d_ws, size_t ws_size,
                              hipStream_t stream) {
    const float* x    = (const float*)d_in[0];   // [N, 64]
    const int*   eIdx = (const int*)d_in[1];     // [2, E]
    const float* eAtt = (const float*)d_in[2];   // [E, 16]
    const float* W1   = (const float*)d_in[3];
    const float* b1   = (const float*)d_in[4];
    const float* W2   = (const float*)d_in[5];
    const float* b2   = (const float*)d_in[6];
    const float* mW1  = (const float*)d_in[7];   // [144,64]: A(0:64), B(64:128), C(128:144)
    const float* mb1  = (const float*)d_in[8];
    const float* mW2  = (const float*)d_in[9];
    const float* mb2  = (const float*)d_in[10];
    float* out = (float*)d_out;                  // [E]

    const int N = N_NODES;
    const int E = N_EDGES;
    const int* row = eIdx;
    const int* col = eIdx + E;

    // workspace layout (all offsets multiples of 16B)
    int*    deg_i  = (int*)d_ws;                        // N
    int*    cnt    = deg_i + N;                         // N
    int*    off    = cnt + N;                           // N
    int*    bsum   = off + N;                           // 256
    float*  dinv   = (float*)(bsum + 256);              // N
    int*    srcIdx = (int*)(dinv + N);                  // E
    __half* h16    = (__half*)(srcIdx + ((E + 63) & ~63)); // N*64*2 halves
    float*  bufB   = (float*)(h16 + (size_t)2 * N * 64);   // N*64 f32
    __half* P16    = h16;
    __half* Q16    = h16 + (size_t)N * 64;

    const int aggBlocks  = (N + 3) / 4;
    const int scanBlocks = (N + 255) / 256;

    // --- CSR build ---
    hipMemsetAsync(deg_i, 0, N * sizeof(int), stream);
    deg_kernel<<<(E + 255) / 256, 256, 0, stream>>>(col, deg_i, E);
    scanA_kernel<<<scanBlocks, 256, 0, stream>>>(deg_i, off, bsum, N);
    scanB_kernel<<<1, 256, 0, stream>>>(bsum, scanBlocks);
    scanC_kernel<<<scanBlocks, 256, 0, stream>>>(deg_i, off, bsum, dinv, cnt, N);
    scatter_kernel<<<(E + 255) / 256, 256, 0, stream>>>(row, col, cnt, srcIdx, E);

    // --- layer 1 ---
    gemm64_reg_kernel<true><<<1024, 256, 0, stream>>>(x, W1, dinv, h16, N);
    agg_csr_kernel<true><<<aggBlocks, 256, 0, stream>>>(
        (const __half2*)h16, off, deg_i, srcIdx, dinv, b1, (float2*)bufB, N);

    // --- layer 2 ---
    gemm64_reg_kernel<true><<<1024, 256, 0, stream>>>(bufB, W2, dinv, h16, N);
    agg_csr_kernel<false><<<aggBlocks, 256, 0, stream>>>(
        (const __half2*)h16, off, deg_i, srcIdx, dinv, b2, (float2*)bufB, N);

    // --- edge MLP decomposition: P16 = h2@A + mb1, Q16 = h2@B ---
    gemmPQ_reg_kernel<<<768, 256, 0, stream>>>(bufB, mW1, mW1 + 64 * 64, mb1, P16, Q16, N);

    edge_mlp3_kernel<<<1024, 256, 0, stream>>>(
        (const float2*)P16, (const float2*)Q16, row, col, (const float4*)eAtt,
        mW1, mW2, mb2, out, E);
}